// Round 14
// baseline (254.370 us; speedup 1.0000x reference)
//
#include <hip/hip_runtime.h>
#include <hip/hip_bf16.h>
#include <math.h>

// VQ quantizer: LDS-free register-sweep bf16-MFMA prefilter + fp32-chain-exact rescore.
//   Exact semantics (validated r2/r4/r6): dist = fl32(fl32(r2+e2) - 2*fma_chain(x.e)),
//   argmin first-min-wins.
// Swapped-operand MFMA: mfma(A=cb_frag, B=z_frag) puts z-row on lane&15 ->
//   per-row running min is in-lane fmin + 2 shfl (no LDS, no barriers).
// Capture rule (r11/r12-validated, stats unchanged): s(c) <= runmin + M; runmin =
//   per-row prefix min, cross-wave shared via device atomicMin(rowMinU); any shared
//   value >= true min -> superset of needed set (2delta~3e-4 <= M=5e-4); stale reads
//   only loosen -> safe. CAP=128; exact full-scan fallback on overflow.
// Round 14 = round 13 resubmitted byte-identical (r13 died on infra:
//   UnresponsiveContainer, same flaky pod as r9; r10 precedent says resubmit).
//   Fit the TRUE VGPR budget (r11/r12 spilled: WRITE_SIZE 16MB = scratch).
//   32 z-rows/wave (Z=64 VGPR), single-buffer A, __launch_bounds__(256,4) ->
//   4 waves/SIMD; 4096 waves (256 row-groups x 16 col-segments).
// Outputs (float32 flat): [loss | quantized(8192*256) | indices(8192 as float)]

#define NROWS 8192
#define DDIM  256
#define KCW   8192
#define CAP   128
#define MARGIN 5e-4f

typedef __attribute__((ext_vector_type(8))) short short8;
typedef __attribute__((ext_vector_type(4))) float f32x4;

__device__ inline unsigned fmap(float f) {
  unsigned b = __float_as_uint(f);
  return (b & 0x80000000u) ? ~b : (b | 0x80000000u);
}
__device__ inline float funmap(unsigned u) {
  unsigned b = (u & 0x80000000u) ? (u & 0x7FFFFFFFu) : ~u;
  return __uint_as_float(b);
}

// Fused: bf16 cast + e2 (f64->f32, cb rows) + rowMinU/cnt init (z rows).
__global__ __launch_bounds__(256) void k_prep_cast(const float* __restrict__ z,
                                                   const float* __restrict__ cb,
                                                   ushort* __restrict__ zb,
                                                   ushort* __restrict__ cbb,
                                                   float* __restrict__ e2f,
                                                   unsigned* __restrict__ rowMinU,
                                                   unsigned* __restrict__ cnt) {
  int t = threadIdx.x, w = t >> 6, lane = t & 63;
  int wid = blockIdx.x * 4 + w;           // 0..16383
  bool isCb = wid >= NROWS;
  int row = isCb ? wid - NROWS : wid;
  const float* src = (isCb ? cb : z) + (size_t)row * DDIM + lane * 4;
  float4 v = *reinterpret_cast<const float4*>(src);
  ushort4 o;
  __hip_bfloat16 bx = __float2bfloat16(v.x); o.x = *(ushort*)&bx;
  __hip_bfloat16 by = __float2bfloat16(v.y); o.y = *(ushort*)&by;
  __hip_bfloat16 bz = __float2bfloat16(v.z); o.z = *(ushort*)&bz;
  __hip_bfloat16 bw = __float2bfloat16(v.w); o.w = *(ushort*)&bw;
  ushort* dst = (isCb ? cbb : zb) + (size_t)row * DDIM + lane * 4;
  *reinterpret_cast<ushort4*>(dst) = o;
  if (isCb) {
    double d = (double)v.x * v.x + (double)v.y * v.y + (double)v.z * v.z + (double)v.w * v.w;
#pragma unroll
    for (int off = 1; off < 64; off <<= 1) d += __shfl_xor(d, off);
    if (lane == 0) e2f[row] = (float)d;
  } else {
    if (lane == 0) { rowMinU[row] = ~0u; cnt[row] = 0; }
  }
}

// Wave: 32 z-rows (2 n-frags x 16 on lane&15), sweeps 512 cb-cols (32 tiles of 16).
// Z resident in 64 VGPR; cb fragments single-buffered (latency hidden by 4 waves/SIMD).
// No LDS, no barriers. wid = rg*16 + sg: rg = 32-row group (0..255), sg = segment.
__global__ __launch_bounds__(256, 4) void k_sweep(const ushort* __restrict__ zb,
                                                  const ushort* __restrict__ cbb,
                                                  const float* __restrict__ e2f,
                                                  unsigned* __restrict__ rowMinU,
                                                  unsigned* __restrict__ cnt,
                                                  ushort* __restrict__ cand) {
  int t = threadIdx.x, w = t >> 6, lane = t & 63;
  int wid = blockIdx.x * 4 + w;           // 0..4095
  int rg = wid >> 4, sg = wid & 15;
  int R0 = rg * 32, C0 = sg * 512;
  int cl = lane & 15, g = lane >> 4;

  // z preload: B-frag layout (z-row on cl, k = kk*32 + g*8)  -> 64 VGPR
  short8 Z[2][8];
#pragma unroll
  for (int n = 0; n < 2; ++n)
#pragma unroll
    for (int kk = 0; kk < 8; ++kk)
      Z[n][kk] = *reinterpret_cast<const short8*>(
          &zb[(size_t)(R0 + n * 16 + cl) * DDIM + kk * 32 + g * 8]);

  int row0 = R0 + cl, row1 = R0 + 16 + cl;
  float runm0 = INFINITY, runm1 = INFINITY;

  for (int tile = 0; tile < 32; ++tile) {
    int CT = C0 + tile * 16;
    // cb A-frag: cb-col on cl, k = kk*32 + g*8  (single buffer)
    short8 A[8];
#pragma unroll
    for (int kk = 0; kk < 8; ++kk)
      A[kk] = *reinterpret_cast<const short8*>(
          &cbb[(size_t)(CT + cl) * DDIM + kk * 32 + g * 8]);
    f32x4 e2v = *reinterpret_cast<const f32x4*>(&e2f[CT + g * 4]);

    f32x4 acc0 = (f32x4){0.f, 0.f, 0.f, 0.f};
    f32x4 acc1 = (f32x4){0.f, 0.f, 0.f, 0.f};
#pragma unroll
    for (int kk = 0; kk < 8; ++kk) {
      acc0 = __builtin_amdgcn_mfma_f32_16x16x32_bf16(A[kk], Z[0][kk], acc0, 0, 0, 0);
      acc1 = __builtin_amdgcn_mfma_f32_16x16x32_bf16(A[kk], Z[1][kk], acc1, 0, 0, 0);
    }

    // D layout: M-idx (cb-col offset) = g*4+j, N-idx (z-row) = cl
    int colb = CT + g * 4;
    {
      float s0 = __fsub_rn(e2v[0], __fmul_rn(2.0f, acc0[0]));
      float s1 = __fsub_rn(e2v[1], __fmul_rn(2.0f, acc0[1]));
      float s2 = __fsub_rn(e2v[2], __fmul_rn(2.0f, acc0[2]));
      float s3 = __fsub_rn(e2v[3], __fmul_rn(2.0f, acc0[3]));
      float jm = fminf(fminf(s0, s1), fminf(s2, s3));
      jm = fminf(jm, __shfl_xor(jm, 16));
      jm = fminf(jm, __shfl_xor(jm, 32));
      runm0 = fminf(runm0, jm);
      float thr = runm0 + MARGIN;
      if (s0 <= thr) { unsigned sl = atomicAdd(&cnt[row0], 1u); if (sl < CAP) cand[(size_t)row0 * CAP + sl] = (ushort)(colb + 0); }
      if (s1 <= thr) { unsigned sl = atomicAdd(&cnt[row0], 1u); if (sl < CAP) cand[(size_t)row0 * CAP + sl] = (ushort)(colb + 1); }
      if (s2 <= thr) { unsigned sl = atomicAdd(&cnt[row0], 1u); if (sl < CAP) cand[(size_t)row0 * CAP + sl] = (ushort)(colb + 2); }
      if (s3 <= thr) { unsigned sl = atomicAdd(&cnt[row0], 1u); if (sl < CAP) cand[(size_t)row0 * CAP + sl] = (ushort)(colb + 3); }
    }
    {
      float s0 = __fsub_rn(e2v[0], __fmul_rn(2.0f, acc1[0]));
      float s1 = __fsub_rn(e2v[1], __fmul_rn(2.0f, acc1[1]));
      float s2 = __fsub_rn(e2v[2], __fmul_rn(2.0f, acc1[2]));
      float s3 = __fsub_rn(e2v[3], __fmul_rn(2.0f, acc1[3]));
      float jm = fminf(fminf(s0, s1), fminf(s2, s3));
      jm = fminf(jm, __shfl_xor(jm, 16));
      jm = fminf(jm, __shfl_xor(jm, 32));
      runm1 = fminf(runm1, jm);
      float thr = runm1 + MARGIN;
      if (s0 <= thr) { unsigned sl = atomicAdd(&cnt[row1], 1u); if (sl < CAP) cand[(size_t)row1 * CAP + sl] = (ushort)(colb + 0); }
      if (s1 <= thr) { unsigned sl = atomicAdd(&cnt[row1], 1u); if (sl < CAP) cand[(size_t)row1 * CAP + sl] = (ushort)(colb + 1); }
      if (s2 <= thr) { unsigned sl = atomicAdd(&cnt[row1], 1u); if (sl < CAP) cand[(size_t)row1 * CAP + sl] = (ushort)(colb + 2); }
      if (s3 <= thr) { unsigned sl = atomicAdd(&cnt[row1], 1u); if (sl < CAP) cand[(size_t)row1 * CAP + sl] = (ushort)(colb + 3); }
    }

    // cross-wave threshold sharing (early-heavy cadence: tiles 0,1,7,15,23,31)
    if (tile < 2 || (tile & 7) == 7) {
      if (g == 0) atomicMin(&rowMinU[row0], fmap(runm0));
      if (g == 1) atomicMin(&rowMinU[row1], fmap(runm1));
      runm0 = fminf(runm0, funmap(rowMinU[row0]));   // stale -> looser -> safe
      runm1 = fminf(runm1, funmap(rowMinU[row1]));
    }
  }
}

// Fused: exact fp32-chain rescore (lex (s,idx) min = first-min-wins) + overflow
// full-scan fallback + gather + per-row loss partial. r2 computed inline.
// Chain loads vectorized to float4 (same IEEE order: x,y,z,w sequential FMAs).
__global__ __launch_bounds__(256) void k_rescore_gather(const float* __restrict__ z,
                                                        const float* __restrict__ cb,
                                                        const float* __restrict__ e2f,
                                                        const unsigned* __restrict__ cnt,
                                                        const ushort* __restrict__ cand,
                                                        float* __restrict__ out_q,
                                                        float* __restrict__ out_idx,
                                                        float* __restrict__ lpart) {
  int t = threadIdx.x, w = t >> 6, lane = t & 63;
  int row = blockIdx.x * 4 + w;
  const float* xp = z + (size_t)row * DDIM;
  const float4* xp4 = reinterpret_cast<const float4*>(xp);
  float4 x4 = xp4[lane];
  double rd = (double)x4.x * x4.x + (double)x4.y * x4.y + (double)x4.z * x4.z + (double)x4.w * x4.w;
#pragma unroll
  for (int off = 1; off < 64; off <<= 1) rd += __shfl_xor(rd, off);
  float r2v = (float)rd;                  // same summation as r6's k_prep (validated)

  unsigned n = cnt[row];
  float s = INFINITY; int ci = 0x7fffffff;
  if (n <= CAP) {
#pragma unroll
    for (int base = 0; base < CAP; base += 64) {
      int k_i = base + lane;
      if (k_i < (int)n) {
        int c = cand[(size_t)row * CAP + k_i];
        const float4* ep4 = reinterpret_cast<const float4*>(cb + (size_t)c * DDIM);
        float acc = 0.f;
#pragma unroll 4
        for (int k4 = 0; k4 < 64; ++k4) {          // k ascending, exact chain order
          float4 e = ep4[k4], x = xp4[k4];
          acc = __fmaf_rn(x.x, e.x, acc);
          acc = __fmaf_rn(x.y, e.y, acc);
          acc = __fmaf_rn(x.z, e.z, acc);
          acc = __fmaf_rn(x.w, e.w, acc);
        }
        float scv = __fsub_rn(__fadd_rn(r2v, e2f[c]), __fmul_rn(2.0f, acc));
        if (scv < s || (scv == s && c < ci)) { s = scv; ci = c; }
      }
    }
  } else {
    for (int base = 0; base < KCW; base += 64) {   // exact full-scan fallback
      int c = base + lane;
      const float4* ep4 = reinterpret_cast<const float4*>(cb + (size_t)c * DDIM);
      float acc = 0.f;
#pragma unroll 4
      for (int k4 = 0; k4 < 64; ++k4) {
        float4 e = ep4[k4], x = xp4[k4];
        acc = __fmaf_rn(x.x, e.x, acc);
        acc = __fmaf_rn(x.y, e.y, acc);
        acc = __fmaf_rn(x.z, e.z, acc);
        acc = __fmaf_rn(x.w, e.w, acc);
      }
      float scv = __fsub_rn(__fadd_rn(r2v, e2f[c]), __fmul_rn(2.0f, acc));
      if (scv < s) { s = scv; ci = c; }            // c ascending: first-wins
    }
  }
#pragma unroll
  for (int off = 1; off < 64; off <<= 1) {         // butterfly: all lanes get min
    float os = __shfl_xor(s, off); int oi = __shfl_xor(ci, off);
    if (os < s || (os == s && oi < ci)) { s = os; ci = oi; }
  }
  if (lane == 0) out_idx[row] = (float)ci;

  float4 qv = *reinterpret_cast<const float4*>(cb + (size_t)ci * DDIM + lane * 4);
  float* o = out_q + (size_t)row * DDIM + lane * 4; // out+1 base: scalar stores
  o[0] = qv.x; o[1] = qv.y; o[2] = qv.z; o[3] = qv.w;
  float dx = qv.x - x4.x, dy = qv.y - x4.y, dz = qv.z - x4.z, dw = qv.w - x4.w;
  double d = (double)dx * dx + (double)dy * dy + (double)dz * dz + (double)dw * dw;
#pragma unroll
  for (int off = 1; off < 64; off <<= 1) d += __shfl_xor(d, off);
  if (lane == 0) lpart[row] = (float)d;
}

__global__ __launch_bounds__(256) void k_loss(const float* __restrict__ lpart,
                                              float* __restrict__ out0) {
  __shared__ double red[256];
  int t = threadIdx.x;
  double s = 0.0;
  for (int j = t; j < NROWS; j += 256) s += lpart[j];  // fixed order -> deterministic
  red[t] = s;
  __syncthreads();
  for (int off = 128; off > 0; off >>= 1) {
    if (t < off) red[t] += red[t + off];
    __syncthreads();
  }
  if (t == 0) out0[0] = (float)(1.25 * red[0] / (double)((size_t)NROWS * DDIM));
}

extern "C" void kernel_launch(void* const* d_in, const int* in_sizes, int n_in,
                              void* d_out, int out_size, void* d_ws, size_t ws_size,
                              hipStream_t stream) {
  const float* z  = (const float*)d_in[0];   // [16,512,256] flat
  const float* cb = (const float*)d_in[1];   // [8192,256]
  float* out = (float*)d_out;
  char* ws = (char*)d_ws;
  const size_t HALF = (size_t)NROWS * DDIM;  // 2,097,152

  // bf16 copies in the out_q region (out+4 floats: 16B-aligned). Last 3 floats
  // of cbb overlap out_idx[0..2]; out_idx is written by k_rescore_gather, which
  // runs after the last zb/cbb read (k_sweep). Recomputed every call.
  ushort* zb  = (ushort*)(out + 4);
  ushort* cbb = zb + HALF;

  // ws: e2f 32K | cnt 32K | rowMinU 32K (lpart overlays it after k_sweep) |
  //     cand ushort 8192*128*2 = 2MB ; total 2,195,456 B (< 2,211,840 proven in r2)
  size_t off = 0;
  float*    e2f     = (float*)(ws + off);    off += NROWS * 4;
  unsigned* cnt     = (unsigned*)(ws + off); off += NROWS * 4;
  unsigned* rowMinU = (unsigned*)(ws + off);
  float*    lpart   = (float*)(ws + off);    off += NROWS * 4;   // overlays rowMinU
  ushort*   cand    = (ushort*)(ws + off);   off += (size_t)NROWS * CAP * 2;

  float* out_q   = out + 1;
  float* out_idx = out + 1 + HALF;

  k_prep_cast     <<<(2 * NROWS) / 4, 256, 0, stream>>>(z, cb, zb, cbb, e2f, rowMinU, cnt);
  k_sweep         <<<1024,            256, 0, stream>>>(zb, cbb, e2f, rowMinU, cnt, cand);
  k_rescore_gather<<<NROWS / 4,       256, 0, stream>>>(z, cb, e2f, cnt, cand, out_q, out_idx, lpart);
  k_loss          <<<1,               256, 0, stream>>>(lpart, out);
}

// Round 15
// 246.345 us; speedup vs baseline: 1.0326x; 1.0326x over previous
//
#include <hip/hip_runtime.h>
#include <hip/hip_bf16.h>
#include <math.h>

// VQ quantizer: SINGLE-PASS bf16-MFMA prefilter (r7 GEMM engine) + fp32-chain-exact
// rescore.  Exact semantics (validated r2/r4/r6): dist = fl32(fl32(r2+e2) -
// 2*fma_chain(x.e)), argmin first-min-wins.
// Online capture (r8-proof): per-row rowMinU via atomicMin; thr = min(returned old,
//   own tile min) + M >= gmin + M. Any c with s_mfma(c) <= gmin + 2delta (~3e-4)
//   satisfies s <= thr (M=5e-4 >= 2delta) -> captured. Races only loosen thr -> safe.
//   CAP=128; exact full-scan fallback on overflow keeps output deterministic.
// Round 15: r7's proven 128x128 global_load_lds GEMM (99.5 us/full-GEMM), ONE pass
//   instead of two, fused min-publish + capture epilogue.
// Outputs (float32 flat): [loss | quantized(8192*256) | indices(8192 as float)]

#define NROWS 8192
#define DDIM  256
#define KCW   8192
#define CAP   128
#define MARGIN 5e-4f

typedef __attribute__((ext_vector_type(8))) short short8;
typedef __attribute__((ext_vector_type(4))) float f32x4;
typedef unsigned int u32;

__device__ inline void async_copy16(void* lds_uniform, const void* gsrc) {
  __builtin_amdgcn_global_load_lds(
      (const __attribute__((address_space(1))) u32*)gsrc,
      (__attribute__((address_space(3))) u32*)lds_uniform, 16, 0, 0);
}

__device__ inline unsigned fmap(float f) {
  unsigned b = __float_as_uint(f);
  return (b & 0x80000000u) ? ~b : (b | 0x80000000u);
}
__device__ inline float funmap(unsigned u) {
  unsigned b = (u & 0x80000000u) ? (u & 0x7FFFFFFFu) : ~u;
  return __uint_as_float(b);
}

// Fused: bf16 cast + e2 (f64->f32, cb rows) + rowMinU/cnt init (z rows).
__global__ __launch_bounds__(256) void k_prep_cast(const float* __restrict__ z,
                                                   const float* __restrict__ cb,
                                                   ushort* __restrict__ zb,
                                                   ushort* __restrict__ cbb,
                                                   float* __restrict__ e2f,
                                                   unsigned* __restrict__ rowMinU,
                                                   unsigned* __restrict__ cnt) {
  int t = threadIdx.x, w = t >> 6, lane = t & 63;
  int wid = blockIdx.x * 4 + w;           // 0..16383
  bool isCb = wid >= NROWS;
  int row = isCb ? wid - NROWS : wid;
  const float* src = (isCb ? cb : z) + (size_t)row * DDIM + lane * 4;
  float4 v = *reinterpret_cast<const float4*>(src);
  ushort4 o;
  __hip_bfloat16 bx = __float2bfloat16(v.x); o.x = *(ushort*)&bx;
  __hip_bfloat16 by = __float2bfloat16(v.y); o.y = *(ushort*)&by;
  __hip_bfloat16 bz = __float2bfloat16(v.z); o.z = *(ushort*)&bz;
  __hip_bfloat16 bw = __float2bfloat16(v.w); o.w = *(ushort*)&bw;
  ushort* dst = (isCb ? cbb : zb) + (size_t)row * DDIM + lane * 4;
  *reinterpret_cast<ushort4*>(dst) = o;
  if (isCb) {
    double d = (double)v.x * v.x + (double)v.y * v.y + (double)v.z * v.z + (double)v.w * v.w;
#pragma unroll
    for (int off = 1; off < 64; off <<= 1) d += __shfl_xor(d, off);
    if (lane == 0) e2f[row] = (float)d;
  } else {
    if (lane == 0) { rowMinU[row] = ~0u; cnt[row] = 0; }
  }
}

// r7's 128x128 tile MFMA GEMM (BK=64, 4 waves each 64x64, global_load_lds staging
// with slot-XOR pre-swizzled source + XOR ds_read — proven 0-conflict, 99.5us),
// single pass with fused min-publish + capture epilogue.
__global__ __launch_bounds__(256) void k_score1(const ushort* __restrict__ zb,
                                                const ushort* __restrict__ cbb,
                                                const float* __restrict__ e2f,
                                                unsigned* __restrict__ rowMinU,
                                                unsigned* __restrict__ cnt,
                                                ushort* __restrict__ cand) {
  __shared__ ushort Ab[128 * 64];
  __shared__ ushort Bb[128 * 64];
  int t = threadIdx.x, w = t >> 6, lane = t & 63;
  int wg = ((blockIdx.x & 7) << 9) | (blockIdx.x >> 3);   // XCD swizzle (4096%8==0)
  int mt = wg >> 6, nt = wg & 63;
  int wm = w >> 1, wn = w & 1;
  int cl = lane & 15, g = lane >> 4;

  // staging geometry (r7): 32 chunks of 1KB (16 A, 16 B); wave w owns chunks w*8..+7.
  int rloc8 = lane >> 3;                 // 0..7
  int sslot = (lane & 7) ^ rloc8;        // pre-swizzled source slot
  const ushort* arow_base = zb  + (size_t)(mt * 128) * DDIM;
  const ushort* brow_base = cbb + (size_t)(nt * 128) * DDIM;

  f32x4 acc[4][4];
#pragma unroll
  for (int m = 0; m < 4; ++m)
#pragma unroll
    for (int n = 0; n < 4; ++n) acc[m][n] = (f32x4){0.f, 0.f, 0.f, 0.f};

  for (int ks = 0; ks < 4; ++ks) {
#pragma unroll
    for (int i = 0; i < 8; ++i) {
      int ch = w * 8 + i;                            // 0..31, uniform per wave
      int ct = ch & 15;                              // tile chunk 0..15
      int row = ct * 8 + rloc8;                      // row within 128-tile
      const ushort* src = (ch < 16)
          ? arow_base + (size_t)row * DDIM + ks * 64 + sslot * 8
          : brow_base + (size_t)row * DDIM + ks * 64 + sslot * 8;
      char* ldsb = (char*)(ch < 16 ? Ab : Bb) + ct * 1024;   // uniform base
      async_copy16(ldsb, src);
    }
    __syncthreads();                                  // drains vmcnt (compiler)
#pragma unroll
    for (int kk = 0; kk < 2; ++kk) {
      short8 af[4], bf[4];
#pragma unroll
      for (int m = 0; m < 4; ++m) {
        int arow = wm * 64 + m * 16 + cl;
        int ab = arow * 128 + (((kk * 4 + g) ^ (arow & 7)) << 4);
        af[m] = *reinterpret_cast<const short8*>((char*)Ab + ab);
      }
#pragma unroll
      for (int n = 0; n < 4; ++n) {
        int brow = wn * 64 + n * 16 + cl;
        int bb = brow * 128 + (((kk * 4 + g) ^ (brow & 7)) << 4);
        bf[n] = *reinterpret_cast<const short8*>((char*)Bb + bb);
      }
#pragma unroll
      for (int m = 0; m < 4; ++m)
#pragma unroll
        for (int n = 0; n < 4; ++n)
          acc[m][n] = __builtin_amdgcn_mfma_f32_16x16x32_bf16(af[m], bf[n], acc[m][n], 0, 0, 0);
    }
    __syncthreads();
  }

  // epilogue: C/D layout col=lane&15, row=(lane>>4)*4+j  [m89/m91]
  int col_base = nt * 128 + wn * 64;
  int row_base = mt * 128 + wm * 64;
  float e2v[4];
#pragma unroll
  for (int n = 0; n < 4; ++n) e2v[n] = e2f[col_base + n * 16 + cl];

#pragma unroll
  for (int m = 0; m < 4; ++m) {
#pragma unroll
    for (int j = 0; j < 4; ++j) {
      int row = row_base + m * 16 + g * 4 + j;
      float s0 = __fsub_rn(e2v[0], __fmul_rn(2.0f, acc[m][0][j]));
      float s1 = __fsub_rn(e2v[1], __fmul_rn(2.0f, acc[m][1][j]));
      float s2 = __fsub_rn(e2v[2], __fmul_rn(2.0f, acc[m][2][j]));
      float s3 = __fsub_rn(e2v[3], __fmul_rn(2.0f, acc[m][3][j]));
      // tile-row min over n and the 16 cl-lanes
      float mn = fminf(fminf(s0, s1), fminf(s2, s3));
#pragma unroll
      for (int off = 1; off < 16; off <<= 1)
        mn = fminf(mn, __shfl_xor(mn, off));
      // publish + freshest bound from the atomic's return value (race-free)
      float thr;
      if (cl == 0) {
        unsigned old = atomicMin(&rowMinU[row], fmap(mn));
        thr = fminf(funmap(old), mn) + MARGIN;
      }
      thr = __shfl(thr, g << 4);          // broadcast from cl==0 lane of this group
      // capture
      if (s0 <= thr) { unsigned sl = atomicAdd(&cnt[row], 1u); if (sl < CAP) cand[(size_t)row * CAP + sl] = (ushort)(col_base + 0 * 16 + cl); }
      if (s1 <= thr) { unsigned sl = atomicAdd(&cnt[row], 1u); if (sl < CAP) cand[(size_t)row * CAP + sl] = (ushort)(col_base + 1 * 16 + cl); }
      if (s2 <= thr) { unsigned sl = atomicAdd(&cnt[row], 1u); if (sl < CAP) cand[(size_t)row * CAP + sl] = (ushort)(col_base + 2 * 16 + cl); }
      if (s3 <= thr) { unsigned sl = atomicAdd(&cnt[row], 1u); if (sl < CAP) cand[(size_t)row * CAP + sl] = (ushort)(col_base + 3 * 16 + cl); }
    }
  }
}

// Fused: exact fp32-chain rescore (lex (s,idx) min = first-min-wins) + overflow
// full-scan fallback + gather + per-row loss partial. r2 computed inline.
// Chain loads vectorized to float4 (same IEEE order: x,y,z,w sequential FMAs).
__global__ __launch_bounds__(256) void k_rescore_gather(const float* __restrict__ z,
                                                        const float* __restrict__ cb,
                                                        const float* __restrict__ e2f,
                                                        const unsigned* __restrict__ cnt,
                                                        const ushort* __restrict__ cand,
                                                        float* __restrict__ out_q,
                                                        float* __restrict__ out_idx,
                                                        float* __restrict__ lpart) {
  int t = threadIdx.x, w = t >> 6, lane = t & 63;
  int row = blockIdx.x * 4 + w;
  const float* xp = z + (size_t)row * DDIM;
  const float4* xp4 = reinterpret_cast<const float4*>(xp);
  float4 x4 = xp4[lane];
  double rd = (double)x4.x * x4.x + (double)x4.y * x4.y + (double)x4.z * x4.z + (double)x4.w * x4.w;
#pragma unroll
  for (int off = 1; off < 64; off <<= 1) rd += __shfl_xor(rd, off);
  float r2v = (float)rd;                  // same summation as r6's k_prep (validated)

  unsigned n = cnt[row];
  float s = INFINITY; int ci = 0x7fffffff;
  if (n <= CAP) {
#pragma unroll
    for (int base = 0; base < CAP; base += 64) {
      int k_i = base + lane;
      if (k_i < (int)n) {
        int c = cand[(size_t)row * CAP + k_i];
        const float4* ep4 = reinterpret_cast<const float4*>(cb + (size_t)c * DDIM);
        float acc = 0.f;
#pragma unroll 4
        for (int k4 = 0; k4 < 64; ++k4) {          // k ascending, exact chain order
          float4 e = ep4[k4], x = xp4[k4];
          acc = __fmaf_rn(x.x, e.x, acc);
          acc = __fmaf_rn(x.y, e.y, acc);
          acc = __fmaf_rn(x.z, e.z, acc);
          acc = __fmaf_rn(x.w, e.w, acc);
        }
        float scv = __fsub_rn(__fadd_rn(r2v, e2f[c]), __fmul_rn(2.0f, acc));
        if (scv < s || (scv == s && c < ci)) { s = scv; ci = c; }
      }
    }
  } else {
    for (int base = 0; base < KCW; base += 64) {   // exact full-scan fallback
      int c = base + lane;
      const float4* ep4 = reinterpret_cast<const float4*>(cb + (size_t)c * DDIM);
      float acc = 0.f;
#pragma unroll 4
      for (int k4 = 0; k4 < 64; ++k4) {
        float4 e = ep4[k4], x = xp4[k4];
        acc = __fmaf_rn(x.x, e.x, acc);
        acc = __fmaf_rn(x.y, e.y, acc);
        acc = __fmaf_rn(x.z, e.z, acc);
        acc = __fmaf_rn(x.w, e.w, acc);
      }
      float scv = __fsub_rn(__fadd_rn(r2v, e2f[c]), __fmul_rn(2.0f, acc));
      if (scv < s) { s = scv; ci = c; }            // c ascending: first-wins
    }
  }
#pragma unroll
  for (int off = 1; off < 64; off <<= 1) {         // butterfly: all lanes get min
    float os = __shfl_xor(s, off); int oi = __shfl_xor(ci, off);
    if (os < s || (os == s && oi < ci)) { s = os; ci = oi; }
  }
  if (lane == 0) out_idx[row] = (float)ci;

  float4 qv = *reinterpret_cast<const float4*>(cb + (size_t)ci * DDIM + lane * 4);
  float* o = out_q + (size_t)row * DDIM + lane * 4; // out+1 base: scalar stores
  o[0] = qv.x; o[1] = qv.y; o[2] = qv.z; o[3] = qv.w;
  float dx = qv.x - x4.x, dy = qv.y - x4.y, dz = qv.z - x4.z, dw = qv.w - x4.w;
  double d = (double)dx * dx + (double)dy * dy + (double)dz * dz + (double)dw * dw;
#pragma unroll
  for (int off = 1; off < 64; off <<= 1) d += __shfl_xor(d, off);
  if (lane == 0) lpart[row] = (float)d;
}

__global__ __launch_bounds__(256) void k_loss(const float* __restrict__ lpart,
                                              float* __restrict__ out0) {
  __shared__ double red[256];
  int t = threadIdx.x;
  double s = 0.0;
  for (int j = t; j < NROWS; j += 256) s += lpart[j];  // fixed order -> deterministic
  red[t] = s;
  __syncthreads();
  for (int off = 128; off > 0; off >>= 1) {
    if (t < off) red[t] += red[t + off];
    __syncthreads();
  }
  if (t == 0) out0[0] = (float)(1.25 * red[0] / (double)((size_t)NROWS * DDIM));
}

extern "C" void kernel_launch(void* const* d_in, const int* in_sizes, int n_in,
                              void* d_out, int out_size, void* d_ws, size_t ws_size,
                              hipStream_t stream) {
  const float* z  = (const float*)d_in[0];   // [16,512,256] flat
  const float* cb = (const float*)d_in[1];   // [8192,256]
  float* out = (float*)d_out;
  char* ws = (char*)d_ws;
  const size_t HALF = (size_t)NROWS * DDIM;  // 2,097,152

  // bf16 copies in the out_q region (out+4 floats: 16B-aligned). Last 3 floats
  // of cbb overlap out_idx[0..2]; out_idx is written by k_rescore_gather, which
  // runs after the last zb/cbb read (k_score1). Recomputed every call.
  ushort* zb  = (ushort*)(out + 4);
  ushort* cbb = zb + HALF;

  // ws: e2f 32K | cnt 32K | rowMinU 32K (lpart overlays it after k_score1) |
  //     cand ushort 8192*128*2 = 2MB ; total 2,195,456 B (< 2,211,840 proven in r2)
  size_t off = 0;
  float*    e2f     = (float*)(ws + off);    off += NROWS * 4;
  unsigned* cnt     = (unsigned*)(ws + off); off += NROWS * 4;
  unsigned* rowMinU = (unsigned*)(ws + off);
  float*    lpart   = (float*)(ws + off);    off += NROWS * 4;   // overlays rowMinU
  ushort*   cand    = (ushort*)(ws + off);   off += (size_t)NROWS * CAP * 2;

  float* out_q   = out + 1;
  float* out_idx = out + 1 + HALF;

  k_prep_cast     <<<(2 * NROWS) / 4, 256, 0, stream>>>(z, cb, zb, cbb, e2f, rowMinU, cnt);
  k_score1        <<<64 * 64,         256, 0, stream>>>(zb, cbb, e2f, rowMinU, cnt, cand);
  k_rescore_gather<<<NROWS / 4,       256, 0, stream>>>(z, cb, e2f, cnt, cand, out_q, out_idx, lpart);
  k_loss          <<<1,               256, 0, stream>>>(lpart, out);
}